// Round 1
// baseline (1785.175 us; speedup 1.0000x reference)
//
#include <hip/hip_runtime.h>

static constexpr int NN = 50000;   // nodes
static constexpr int NE = 800000;  // edges
static constexpr int D0 = 128;     // in dim
static constexpr int D1 = 256;     // hidden
static constexpr int D2 = 5;       // out

// workspace layout (floats). cnt+agg1+agg2 contiguous -> single memset.
static constexpr size_t OFF_CNT  = 0;
static constexpr size_t OFF_AGG1 = OFF_CNT  + NN;            // 50000*128
static constexpr size_t OFF_AGG2 = OFF_AGG1 + (size_t)NN*D0; // 50000*5
static constexpr size_t OFF_INV  = OFF_AGG2 + (size_t)NN*D2;
static constexpr size_t OFF_H    = OFF_INV  + NN;            // 50000*256
static constexpr size_t OFF_T    = OFF_H    + (size_t)NN*D1; // 50000*5
static constexpr size_t OFF_R    = OFF_T    + (size_t)NN*D2; // 50000*5

// ---------------------------------------------------------------- scatter 1
// one 32-thread group per edge; each thread moves one float4 (128 floats/row)
__global__ __launch_bounds__(256) void k_scatter1(
    const float* __restrict__ x, const int* __restrict__ src,
    const int* __restrict__ dst, float* __restrict__ agg1,
    float* __restrict__ cnt) {
  int tid = blockIdx.x * blockDim.x + threadIdx.x;
  int e = tid >> 5, c = tid & 31;
  if (e >= NE) return;
  int s = src[e], d = dst[e];
  if (c == 0) unsafeAtomicAdd(&cnt[d], 1.0f);
  const float4 v = *(const float4*)(x + (size_t)s * D0 + c * 4);
  float* dp = agg1 + (size_t)d * D0 + c * 4;
  unsafeAtomicAdd(dp + 0, v.x);
  unsafeAtomicAdd(dp + 1, v.y);
  unsafeAtomicAdd(dp + 2, v.z);
  unsafeAtomicAdd(dp + 3, v.w);
}

__global__ __launch_bounds__(256) void k_inv(const float* __restrict__ cnt,
                                             float* __restrict__ inv) {
  int i = blockIdx.x * blockDim.x + threadIdx.x;
  if (i < NN) inv[i] = 1.0f / fmaxf(cnt[i], 1.0f);
}

// ---------------------------------------------------------------- GEMM 1
// h = relu( [mean | x] @ [W1l | W1r]^T + b1l )
// M=50000, K=256 (virtual), N=256. Tile 64x64, BK=32, 256 thr, 4x4 micro.
__global__ __launch_bounds__(256) void k_gemm1(
    const float* __restrict__ agg1, const float* __restrict__ inv,
    const float* __restrict__ x, const float* __restrict__ W1l,
    const float* __restrict__ W1r, const float* __restrict__ b1l,
    float* __restrict__ h) {
  __shared__ float sA[32 * 68];  // [k][i], pad 68 keeps 16B align + bank spread
  __shared__ float sB[32 * 68];  // [k][j]
  const int tid = threadIdx.x;
  const int row0 = blockIdx.y * 64;
  const int col0 = blockIdx.x * 64;
  const int ty = tid >> 4, tx = tid & 15;
  const int li = tid >> 2;        // 0..63: tile row (A) / tile col (B)
  const int lk = (tid & 3) * 8;   // 0,8,16,24: k sub-offset (8 consecutive)
  float acc[4][4] = {};

  for (int kk = 0; kk < 256; kk += 32) {
    // --- load A tile (64 rows x 32 k)
    {
      const int gr = row0 + li;
      float4 v0 = {0, 0, 0, 0}, v1 = {0, 0, 0, 0};
      if (gr < NN) {
        if (kk < 128) {
          const float* base = agg1 + (size_t)gr * D0 + kk + lk;
          const float sc = inv[gr];
          v0 = *(const float4*)(base);
          v1 = *(const float4*)(base + 4);
          v0.x *= sc; v0.y *= sc; v0.z *= sc; v0.w *= sc;
          v1.x *= sc; v1.y *= sc; v1.z *= sc; v1.w *= sc;
        } else {
          const float* base = x + (size_t)gr * D0 + (kk - 128) + lk;
          v0 = *(const float4*)(base);
          v1 = *(const float4*)(base + 4);
        }
      }
      sA[(lk + 0) * 68 + li] = v0.x;
      sA[(lk + 1) * 68 + li] = v0.y;
      sA[(lk + 2) * 68 + li] = v0.z;
      sA[(lk + 3) * 68 + li] = v0.w;
      sA[(lk + 4) * 68 + li] = v1.x;
      sA[(lk + 5) * 68 + li] = v1.y;
      sA[(lk + 6) * 68 + li] = v1.z;
      sA[(lk + 7) * 68 + li] = v1.w;
    }
    // --- load B tile (64 cols x 32 k)  B[j,k] = Wv[col0+j][kk+k]
    {
      const int gc = col0 + li;  // < 256 always
      const float* wbase =
          (kk < 128 ? W1l : W1r) + (size_t)gc * D0 + (kk & 127) + lk;
      const float4 w0 = *(const float4*)(wbase);
      const float4 w1 = *(const float4*)(wbase + 4);
      sB[(lk + 0) * 68 + li] = w0.x;
      sB[(lk + 1) * 68 + li] = w0.y;
      sB[(lk + 2) * 68 + li] = w0.z;
      sB[(lk + 3) * 68 + li] = w0.w;
      sB[(lk + 4) * 68 + li] = w1.x;
      sB[(lk + 5) * 68 + li] = w1.y;
      sB[(lk + 6) * 68 + li] = w1.z;
      sB[(lk + 7) * 68 + li] = w1.w;
    }
    __syncthreads();
#pragma unroll
    for (int k = 0; k < 32; ++k) {
      const float4 a = *(const float4*)&sA[k * 68 + ty * 4];
      const float4 b = *(const float4*)&sB[k * 68 + tx * 4];
      const float av[4] = {a.x, a.y, a.z, a.w};
      const float bv[4] = {b.x, b.y, b.z, b.w};
#pragma unroll
      for (int rr = 0; rr < 4; ++rr)
#pragma unroll
        for (int cc = 0; cc < 4; ++cc) acc[rr][cc] += av[rr] * bv[cc];
    }
    __syncthreads();
  }

  const float4 bias = *(const float4*)(b1l + col0 + tx * 4);
  const float bb[4] = {bias.x, bias.y, bias.z, bias.w};
#pragma unroll
  for (int rr = 0; rr < 4; ++rr) {
    const int gr = row0 + ty * 4 + rr;
    if (gr < NN) {
      float4 o;
      o.x = fmaxf(acc[rr][0] + bb[0], 0.f);
      o.y = fmaxf(acc[rr][1] + bb[1], 0.f);
      o.z = fmaxf(acc[rr][2] + bb[2], 0.f);
      o.w = fmaxf(acc[rr][3] + bb[3], 0.f);
      *(float4*)(h + (size_t)gr * D1 + col0 + tx * 4) = o;
    }
  }
}

// ---------------------------------------------------------------- layer-2 lin
// t = h @ W2l^T, r = h @ W2r^T  (one thread per node, W2 in LDS broadcast)
__global__ __launch_bounds__(256) void k_lin2(
    const float* __restrict__ h, const float* __restrict__ W2l,
    const float* __restrict__ W2r, float* __restrict__ t,
    float* __restrict__ r) {
  __shared__ float sWl[D2 * D1];
  __shared__ float sWr[D2 * D1];
  for (int idx = threadIdx.x; idx < 2 * D2 * D1; idx += 256) {
    if (idx < D2 * D1) sWl[idx] = W2l[idx];
    else sWr[idx - D2 * D1] = W2r[idx - D2 * D1];
  }
  __syncthreads();
  const int i = blockIdx.x * blockDim.x + threadIdx.x;
  if (i >= NN) return;
  float accl[5] = {}, accr[5] = {};
  const float* hr = h + (size_t)i * D1;
  for (int k = 0; k < D1; k += 4) {
    const float4 hv = *(const float4*)(hr + k);
#pragma unroll
    for (int n = 0; n < 5; ++n) {
      accl[n] += hv.x * sWl[n * D1 + k] + hv.y * sWl[n * D1 + k + 1] +
                 hv.z * sWl[n * D1 + k + 2] + hv.w * sWl[n * D1 + k + 3];
      accr[n] += hv.x * sWr[n * D1 + k] + hv.y * sWr[n * D1 + k + 1] +
                 hv.z * sWr[n * D1 + k + 2] + hv.w * sWr[n * D1 + k + 3];
    }
  }
#pragma unroll
  for (int n = 0; n < 5; ++n) {
    t[(size_t)i * D2 + n] = accl[n];
    r[(size_t)i * D2 + n] = accr[n];
  }
}

// ---------------------------------------------------------------- scatter 2
__global__ __launch_bounds__(256) void k_scatter2(
    const float* __restrict__ t, const int* __restrict__ src,
    const int* __restrict__ dst, float* __restrict__ agg2) {
  const int e = blockIdx.x * blockDim.x + threadIdx.x;
  if (e >= NE) return;
  const int s = src[e], d = dst[e];
  const float* tp = t + (size_t)s * D2;
  float* dp = agg2 + (size_t)d * D2;
#pragma unroll
  for (int n = 0; n < 5; ++n) unsafeAtomicAdd(dp + n, tp[n]);
}

// ---------------------------------------------------------------- epilogue
__global__ __launch_bounds__(256) void k_final(
    const float* __restrict__ agg2, const float* __restrict__ inv,
    const float* __restrict__ r, const float* __restrict__ b2l,
    float* __restrict__ out) {
  const int tid = blockIdx.x * blockDim.x + threadIdx.x;
  if (tid >= NN * D2) return;
  const int i = tid / D2;
  const int n = tid - i * D2;
  out[tid] = fmaxf(agg2[tid] * inv[i] + b2l[n] + r[tid], 0.f);
}

extern "C" void kernel_launch(void* const* d_in, const int* in_sizes, int n_in,
                              void* d_out, int out_size, void* d_ws,
                              size_t ws_size, hipStream_t stream) {
  const float* x   = (const float*)d_in[0];
  const int*   ei  = (const int*)d_in[1];
  const int*   src = ei;
  const int*   dst = ei + NE;
  const float* W1l = (const float*)d_in[2];
  const float* b1l = (const float*)d_in[3];
  const float* W1r = (const float*)d_in[4];
  const float* W2l = (const float*)d_in[5];
  const float* b2l = (const float*)d_in[6];
  const float* W2r = (const float*)d_in[7];
  float* out = (float*)d_out;

  float* ws   = (float*)d_ws;
  float* cnt  = ws + OFF_CNT;
  float* agg1 = ws + OFF_AGG1;
  float* agg2 = ws + OFF_AGG2;
  float* inv  = ws + OFF_INV;
  float* h    = ws + OFF_H;
  float* t    = ws + OFF_T;
  float* r    = ws + OFF_R;

  // zero cnt + agg1 + agg2 (contiguous)
  hipMemsetAsync(ws, 0, (size_t)(NN + (size_t)NN * D0 + (size_t)NN * D2) * 4,
                 stream);

  k_scatter1<<<(NE * 32) / 256, 256, 0, stream>>>(x, src, dst, agg1, cnt);
  k_inv<<<(NN + 255) / 256, 256, 0, stream>>>(cnt, inv);
  dim3 g1(4, (NN + 63) / 64);
  k_gemm1<<<g1, 256, 0, stream>>>(agg1, inv, x, W1l, W1r, b1l, h);
  k_lin2<<<(NN + 255) / 256, 256, 0, stream>>>(h, W2l, W2r, t, r);
  k_scatter2<<<(NE + 255) / 256, 256, 0, stream>>>(t, src, dst, agg2);
  k_final<<<(NN * D2 + 255) / 256, 256, 0, stream>>>(agg2, inv, r, b2l, out);
}

// Round 2
// 475.609 us; speedup vs baseline: 3.7534x; 3.7534x over previous
//
#include <hip/hip_runtime.h>

static constexpr int NN = 50000;   // nodes
static constexpr int NE = 800000;  // edges
static constexpr int D0 = 128;     // in dim
static constexpr int D1 = 256;     // hidden
static constexpr int D2 = 5;       // out

// ---------------------------------------------------------------- CSR build
__global__ __launch_bounds__(256) void k_hist(const int* __restrict__ dst,
                                              int* __restrict__ deg) {
  int e = blockIdx.x * blockDim.x + threadIdx.x;
  if (e < NE) atomicAdd(&deg[dst[e]], 1);
}

// single block: exclusive scan of deg -> cur (start offsets), inv = 1/max(deg,1)
__global__ __launch_bounds__(256) void k_scan(const int* __restrict__ deg,
                                              int* __restrict__ cur,
                                              float* __restrict__ inv) {
  __shared__ int part[256];
  const int t = threadIdx.x;
  const int CH = (NN + 255) / 256;  // 196
  const int lo = t * CH, hi = min(lo + CH, NN);
  int s = 0;
  for (int i = lo; i < hi; ++i) s += deg[i];
  part[t] = s;
  __syncthreads();
  for (int d = 1; d < 256; d <<= 1) {
    int v = (t >= d) ? part[t - d] : 0;
    __syncthreads();
    part[t] += v;
    __syncthreads();
  }
  int run = (t == 0) ? 0 : part[t - 1];
  for (int i = lo; i < hi; ++i) {
    const int d = deg[i];
    cur[i] = run;
    inv[i] = 1.0f / (float)max(d, 1);
    run += d;
  }
}

// bucket-scatter src into CSR order; cur[i] advances to END offset (= begin of i+1)
__global__ __launch_bounds__(256) void k_sortedges(const int* __restrict__ src,
                                                   const int* __restrict__ dst,
                                                   int* __restrict__ cur,
                                                   int* __restrict__ esort) {
  int e = blockIdx.x * blockDim.x + threadIdx.x;
  if (e < NE) {
    int p = atomicAdd(&cur[dst[e]], 1);
    esort[p] = src[e];
  }
}

// ---------------------------------------------------------------- aggregate 1
// one wave per node; lane covers 2 floats. after sort, cur[i] = end(i), begin = cur[i-1]
__global__ __launch_bounds__(256) void k_agg1(
    const float* __restrict__ x, const int* __restrict__ esort,
    const int* __restrict__ cur, const float* __restrict__ inv,
    float* __restrict__ mean) {
  const int wave = (blockIdx.x * 256 + threadIdx.x) >> 6;
  const int lane = threadIdx.x & 63;
  if (wave >= NN) return;
  const int i = wave;
  int e = (i == 0) ? 0 : cur[i - 1];
  const int end = cur[i];
  float2 a0 = {0.f, 0.f}, a1 = {0.f, 0.f};
  const float* xb = x + lane * 2;
  for (; e + 1 < end; e += 2) {
    const int s0 = esort[e], s1 = esort[e + 1];
    const float2 v0 = *(const float2*)(xb + (size_t)s0 * D0);
    const float2 v1 = *(const float2*)(xb + (size_t)s1 * D0);
    a0.x += v0.x; a0.y += v0.y;
    a1.x += v1.x; a1.y += v1.y;
  }
  if (e < end) {
    const int s0 = esort[e];
    const float2 v0 = *(const float2*)(xb + (size_t)s0 * D0);
    a0.x += v0.x; a0.y += v0.y;
  }
  const float sc = inv[i];
  float2 m;
  m.x = (a0.x + a1.x) * sc;
  m.y = (a0.y + a1.y) * sc;
  *(float2*)(mean + (size_t)i * D0 + lane * 2) = m;
}

// ---------------------------------------------------------------- GEMM 1
// h = relu( [mean | x] @ [W1l | W1r]^T + b1l )
// M=50000, K=256 (virtual), N=256. Tile 64x64, BK=32, 256 thr, 4x4 micro.
__global__ __launch_bounds__(256) void k_gemm1(
    const float* __restrict__ mean, const float* __restrict__ x,
    const float* __restrict__ W1l, const float* __restrict__ W1r,
    const float* __restrict__ b1l, float* __restrict__ h) {
  __shared__ float sA[32 * 68];
  __shared__ float sB[32 * 68];
  const int tid = threadIdx.x;
  const int row0 = blockIdx.y * 64;
  const int col0 = blockIdx.x * 64;
  const int ty = tid >> 4, tx = tid & 15;
  const int li = tid >> 2;
  const int lk = (tid & 3) * 8;
  float acc[4][4] = {};

  for (int kk = 0; kk < 256; kk += 32) {
    {
      const int gr = row0 + li;
      float4 v0 = {0, 0, 0, 0}, v1 = {0, 0, 0, 0};
      if (gr < NN) {
        const float* base =
            (kk < 128 ? mean : x) + (size_t)gr * D0 + (kk & 127) + lk;
        v0 = *(const float4*)(base);
        v1 = *(const float4*)(base + 4);
      }
      sA[(lk + 0) * 68 + li] = v0.x;
      sA[(lk + 1) * 68 + li] = v0.y;
      sA[(lk + 2) * 68 + li] = v0.z;
      sA[(lk + 3) * 68 + li] = v0.w;
      sA[(lk + 4) * 68 + li] = v1.x;
      sA[(lk + 5) * 68 + li] = v1.y;
      sA[(lk + 6) * 68 + li] = v1.z;
      sA[(lk + 7) * 68 + li] = v1.w;
    }
    {
      const int gc = col0 + li;
      const float* wbase =
          (kk < 128 ? W1l : W1r) + (size_t)gc * D0 + (kk & 127) + lk;
      const float4 w0 = *(const float4*)(wbase);
      const float4 w1 = *(const float4*)(wbase + 4);
      sB[(lk + 0) * 68 + li] = w0.x;
      sB[(lk + 1) * 68 + li] = w0.y;
      sB[(lk + 2) * 68 + li] = w0.z;
      sB[(lk + 3) * 68 + li] = w0.w;
      sB[(lk + 4) * 68 + li] = w1.x;
      sB[(lk + 5) * 68 + li] = w1.y;
      sB[(lk + 6) * 68 + li] = w1.z;
      sB[(lk + 7) * 68 + li] = w1.w;
    }
    __syncthreads();
#pragma unroll
    for (int k = 0; k < 32; ++k) {
      const float4 a = *(const float4*)&sA[k * 68 + ty * 4];
      const float4 b = *(const float4*)&sB[k * 68 + tx * 4];
      const float av[4] = {a.x, a.y, a.z, a.w};
      const float bv[4] = {b.x, b.y, b.z, b.w};
#pragma unroll
      for (int rr = 0; rr < 4; ++rr)
#pragma unroll
        for (int cc = 0; cc < 4; ++cc) acc[rr][cc] += av[rr] * bv[cc];
    }
    __syncthreads();
  }

  const float4 bias = *(const float4*)(b1l + col0 + tx * 4);
  const float bb[4] = {bias.x, bias.y, bias.z, bias.w};
#pragma unroll
  for (int rr = 0; rr < 4; ++rr) {
    const int gr = row0 + ty * 4 + rr;
    if (gr < NN) {
      float4 o;
      o.x = fmaxf(acc[rr][0] + bb[0], 0.f);
      o.y = fmaxf(acc[rr][1] + bb[1], 0.f);
      o.z = fmaxf(acc[rr][2] + bb[2], 0.f);
      o.w = fmaxf(acc[rr][3] + bb[3], 0.f);
      *(float4*)(h + (size_t)gr * D1 + col0 + tx * 4) = o;
    }
  }
}

// ---------------------------------------------------------------- layer-2 lin
__global__ __launch_bounds__(256) void k_lin2(
    const float* __restrict__ h, const float* __restrict__ W2l,
    const float* __restrict__ W2r, float* __restrict__ t,
    float* __restrict__ r) {
  __shared__ float sWl[D2 * D1];
  __shared__ float sWr[D2 * D1];
  for (int idx = threadIdx.x; idx < 2 * D2 * D1; idx += 256) {
    if (idx < D2 * D1) sWl[idx] = W2l[idx];
    else sWr[idx - D2 * D1] = W2r[idx - D2 * D1];
  }
  __syncthreads();
  const int i = blockIdx.x * blockDim.x + threadIdx.x;
  if (i >= NN) return;
  float accl[5] = {}, accr[5] = {};
  const float* hr = h + (size_t)i * D1;
  for (int k = 0; k < D1; k += 4) {
    const float4 hv = *(const float4*)(hr + k);
#pragma unroll
    for (int n = 0; n < 5; ++n) {
      accl[n] += hv.x * sWl[n * D1 + k] + hv.y * sWl[n * D1 + k + 1] +
                 hv.z * sWl[n * D1 + k + 2] + hv.w * sWl[n * D1 + k + 3];
      accr[n] += hv.x * sWr[n * D1 + k] + hv.y * sWr[n * D1 + k + 1] +
                 hv.z * sWr[n * D1 + k + 2] + hv.w * sWr[n * D1 + k + 3];
    }
  }
#pragma unroll
  for (int n = 0; n < 5; ++n) {
    t[(size_t)i * D2 + n] = accl[n];
    r[(size_t)i * D2 + n] = accr[n];
  }
}

// ---------------------------------------------------------------- layer-2 agg + epilogue
__global__ __launch_bounds__(256) void k_layer2(
    const float* __restrict__ t, const float* __restrict__ r,
    const int* __restrict__ esort, const int* __restrict__ cur,
    const float* __restrict__ inv, const float* __restrict__ b2l,
    float* __restrict__ out) {
  const int i = blockIdx.x * blockDim.x + threadIdx.x;
  if (i >= NN) return;
  float acc[5] = {};
  int e = (i == 0) ? 0 : cur[i - 1];
  const int end = cur[i];
  for (; e < end; ++e) {
    const float* tp = t + (size_t)esort[e] * D2;
#pragma unroll
    for (int n = 0; n < 5; ++n) acc[n] += tp[n];
  }
  const float sc = inv[i];
  const float* rp = r + (size_t)i * D2;
#pragma unroll
  for (int n = 0; n < 5; ++n)
    out[(size_t)i * D2 + n] = fmaxf(acc[n] * sc + b2l[n] + rp[n], 0.f);
}

extern "C" void kernel_launch(void* const* d_in, const int* in_sizes, int n_in,
                              void* d_out, int out_size, void* d_ws,
                              size_t ws_size, hipStream_t stream) {
  const float* x   = (const float*)d_in[0];
  const int*   ei  = (const int*)d_in[1];
  const int*   src = ei;
  const int*   dst = ei + NE;
  const float* W1l = (const float*)d_in[2];
  const float* b1l = (const float*)d_in[3];
  const float* W1r = (const float*)d_in[4];
  const float* W2l = (const float*)d_in[5];
  const float* b2l = (const float*)d_in[6];
  const float* W2r = (const float*)d_in[7];
  float* out = (float*)d_out;

  // workspace layout (4-byte units)
  int*   deg   = (int*)d_ws;                 // NN
  int*   cur   = deg + NN;                   // NN (start offsets -> end offsets after sort)
  int*   esort = cur + NN;                   // NE
  float* inv   = (float*)(esort + NE);       // NN
  float* mean  = inv + NN;                   // NN*D0
  float* h     = mean + (size_t)NN * D0;     // NN*D1
  float* t     = mean;                       // alias: mean dead after k_gemm1
  float* r     = mean + (size_t)NN * D2;     // alias

  hipMemsetAsync(deg, 0, (size_t)NN * sizeof(int), stream);

  k_hist<<<(NE + 255) / 256, 256, 0, stream>>>(dst, deg);
  k_scan<<<1, 256, 0, stream>>>(deg, cur, inv);
  k_sortedges<<<(NE + 255) / 256, 256, 0, stream>>>(src, dst, cur, esort);
  k_agg1<<<(NN * 64 + 255) / 256, 256, 0, stream>>>(x, esort, cur, inv, mean);
  dim3 g1(4, (NN + 63) / 64);
  k_gemm1<<<g1, 256, 0, stream>>>(mean, x, W1l, W1r, b1l, h);
  k_lin2<<<(NN + 255) / 256, 256, 0, stream>>>(h, W2l, W2r, t, r);
  k_layer2<<<(NN + 255) / 256, 256, 0, stream>>>(t, r, esort, cur, inv, b2l, out);
}

// Round 3
// 362.843 us; speedup vs baseline: 4.9200x; 1.3108x over previous
//
#include <hip/hip_runtime.h>

static constexpr int NN = 50000;   // nodes
static constexpr int NE = 800000;  // edges
static constexpr int D0 = 128;     // in dim
static constexpr int D1 = 256;     // hidden
static constexpr int D2 = 5;       // out
static constexpr int NB = (NN + 255) / 256;  // 196 scan blocks

// ---------------------------------------------------------------- CSR build
__global__ __launch_bounds__(256) void k_hist(const int* __restrict__ dst,
                                              int* __restrict__ deg) {
  int e = blockIdx.x * blockDim.x + threadIdx.x;
  if (e < NE) atomicAdd(&deg[dst[e]], 1);
}

// Phase A: per-block exclusive scan of deg -> cur (block-local), block sums -> bsum
__global__ __launch_bounds__(256) void k_scanA(const int* __restrict__ deg,
                                               int* __restrict__ cur,
                                               int* __restrict__ bsum) {
  __shared__ int s[256];
  const int t = threadIdx.x;
  const int i = blockIdx.x * 256 + t;
  const int v = (i < NN) ? deg[i] : 0;
  s[t] = v;
  __syncthreads();
  for (int d = 1; d < 256; d <<= 1) {
    int u = (t >= d) ? s[t - d] : 0;
    __syncthreads();
    s[t] += u;
    __syncthreads();
  }
  if (i < NN) cur[i] = s[t] - v;  // block-local exclusive
  if (t == 255) bsum[blockIdx.x] = s[255];
}

// Phase B: every block scans the 196 block sums in LDS, adds its offset,
// finalizes cur (global exclusive start offsets) and inv = 1/max(deg,1).
__global__ __launch_bounds__(256) void k_scanB(const int* __restrict__ deg,
                                               const int* __restrict__ bsum,
                                               int* __restrict__ cur,
                                               float* __restrict__ inv) {
  __shared__ int s[256];
  const int t = threadIdx.x;
  s[t] = (t < NB) ? bsum[t] : 0;
  __syncthreads();
  for (int d = 1; d < 256; d <<= 1) {
    int u = (t >= d) ? s[t - d] : 0;
    __syncthreads();
    s[t] += u;
    __syncthreads();
  }
  const int boff = (blockIdx.x == 0) ? 0 : s[blockIdx.x - 1];
  const int i = blockIdx.x * 256 + t;
  if (i < NN) {
    cur[i] += boff;
    inv[i] = 1.0f / (float)max(deg[i], 1);
  }
}

// bucket-scatter src into CSR order; cur[i] advances to END offset (= begin of i+1)
__global__ __launch_bounds__(256) void k_sortedges(const int* __restrict__ src,
                                                   const int* __restrict__ dst,
                                                   int* __restrict__ cur,
                                                   int* __restrict__ esort) {
  int e = blockIdx.x * blockDim.x + threadIdx.x;
  if (e < NE) {
    int p = atomicAdd(&cur[dst[e]], 1);
    esort[p] = src[e];
  }
}

// ---------------------------------------------------------------- aggregate 1
// one wave per node; lane covers 2 floats. after sort, cur[i] = end(i), begin = cur[i-1]
__global__ __launch_bounds__(256) void k_agg1(
    const float* __restrict__ x, const int* __restrict__ esort,
    const int* __restrict__ cur, const float* __restrict__ inv,
    float* __restrict__ mean) {
  const int wave = (blockIdx.x * 256 + threadIdx.x) >> 6;
  const int lane = threadIdx.x & 63;
  if (wave >= NN) return;
  const int i = wave;
  int e = (i == 0) ? 0 : cur[i - 1];
  const int end = cur[i];
  float2 a0 = {0.f, 0.f}, a1 = {0.f, 0.f};
  const float* xb = x + lane * 2;
  for (; e + 1 < end; e += 2) {
    const int s0 = esort[e], s1 = esort[e + 1];
    const float2 v0 = *(const float2*)(xb + (size_t)s0 * D0);
    const float2 v1 = *(const float2*)(xb + (size_t)s1 * D0);
    a0.x += v0.x; a0.y += v0.y;
    a1.x += v1.x; a1.y += v1.y;
  }
  if (e < end) {
    const int s0 = esort[e];
    const float2 v0 = *(const float2*)(xb + (size_t)s0 * D0);
    a0.x += v0.x; a0.y += v0.y;
  }
  const float sc = inv[i];
  float2 m;
  m.x = (a0.x + a1.x) * sc;
  m.y = (a0.y + a1.y) * sc;
  *(float2*)(mean + (size_t)i * D0 + lane * 2) = m;
}

// ---------------------------------------------------------------- GEMM 1
// h = relu( [mean | x] @ [W1l | W1r]^T + b1l )
__global__ __launch_bounds__(256) void k_gemm1(
    const float* __restrict__ mean, const float* __restrict__ x,
    const float* __restrict__ W1l, const float* __restrict__ W1r,
    const float* __restrict__ b1l, float* __restrict__ h) {
  __shared__ float sA[32 * 68];
  __shared__ float sB[32 * 68];
  const int tid = threadIdx.x;
  const int row0 = blockIdx.y * 64;
  const int col0 = blockIdx.x * 64;
  const int ty = tid >> 4, tx = tid & 15;
  const int li = tid >> 2;
  const int lk = (tid & 3) * 8;
  float acc[4][4] = {};

  for (int kk = 0; kk < 256; kk += 32) {
    {
      const int gr = row0 + li;
      float4 v0 = {0, 0, 0, 0}, v1 = {0, 0, 0, 0};
      if (gr < NN) {
        const float* base =
            (kk < 128 ? mean : x) + (size_t)gr * D0 + (kk & 127) + lk;
        v0 = *(const float4*)(base);
        v1 = *(const float4*)(base + 4);
      }
      sA[(lk + 0) * 68 + li] = v0.x;
      sA[(lk + 1) * 68 + li] = v0.y;
      sA[(lk + 2) * 68 + li] = v0.z;
      sA[(lk + 3) * 68 + li] = v0.w;
      sA[(lk + 4) * 68 + li] = v1.x;
      sA[(lk + 5) * 68 + li] = v1.y;
      sA[(lk + 6) * 68 + li] = v1.z;
      sA[(lk + 7) * 68 + li] = v1.w;
    }
    {
      const int gc = col0 + li;
      const float* wbase =
          (kk < 128 ? W1l : W1r) + (size_t)gc * D0 + (kk & 127) + lk;
      const float4 w0 = *(const float4*)(wbase);
      const float4 w1 = *(const float4*)(wbase + 4);
      sB[(lk + 0) * 68 + li] = w0.x;
      sB[(lk + 1) * 68 + li] = w0.y;
      sB[(lk + 2) * 68 + li] = w0.z;
      sB[(lk + 3) * 68 + li] = w0.w;
      sB[(lk + 4) * 68 + li] = w1.x;
      sB[(lk + 5) * 68 + li] = w1.y;
      sB[(lk + 6) * 68 + li] = w1.z;
      sB[(lk + 7) * 68 + li] = w1.w;
    }
    __syncthreads();
#pragma unroll
    for (int k = 0; k < 32; ++k) {
      const float4 a = *(const float4*)&sA[k * 68 + ty * 4];
      const float4 b = *(const float4*)&sB[k * 68 + tx * 4];
      const float av[4] = {a.x, a.y, a.z, a.w};
      const float bv[4] = {b.x, b.y, b.z, b.w};
#pragma unroll
      for (int rr = 0; rr < 4; ++rr)
#pragma unroll
        for (int cc = 0; cc < 4; ++cc) acc[rr][cc] += av[rr] * bv[cc];
    }
    __syncthreads();
  }

  const float4 bias = *(const float4*)(b1l + col0 + tx * 4);
  const float bb[4] = {bias.x, bias.y, bias.z, bias.w};
#pragma unroll
  for (int rr = 0; rr < 4; ++rr) {
    const int gr = row0 + ty * 4 + rr;
    if (gr < NN) {
      float4 o;
      o.x = fmaxf(acc[rr][0] + bb[0], 0.f);
      o.y = fmaxf(acc[rr][1] + bb[1], 0.f);
      o.z = fmaxf(acc[rr][2] + bb[2], 0.f);
      o.w = fmaxf(acc[rr][3] + bb[3], 0.f);
      *(float4*)(h + (size_t)gr * D1 + col0 + tx * 4) = o;
    }
  }
}

// ---------------------------------------------------------------- layer-2 lin
__global__ __launch_bounds__(256) void k_lin2(
    const float* __restrict__ h, const float* __restrict__ W2l,
    const float* __restrict__ W2r, float* __restrict__ t,
    float* __restrict__ r) {
  __shared__ float sWl[D2 * D1];
  __shared__ float sWr[D2 * D1];
  for (int idx = threadIdx.x; idx < 2 * D2 * D1; idx += 256) {
    if (idx < D2 * D1) sWl[idx] = W2l[idx];
    else sWr[idx - D2 * D1] = W2r[idx - D2 * D1];
  }
  __syncthreads();
  const int i = blockIdx.x * blockDim.x + threadIdx.x;
  if (i >= NN) return;
  float accl[5] = {}, accr[5] = {};
  const float* hr = h + (size_t)i * D1;
  for (int k = 0; k < D1; k += 4) {
    const float4 hv = *(const float4*)(hr + k);
#pragma unroll
    for (int n = 0; n < 5; ++n) {
      accl[n] += hv.x * sWl[n * D1 + k] + hv.y * sWl[n * D1 + k + 1] +
                 hv.z * sWl[n * D1 + k + 2] + hv.w * sWl[n * D1 + k + 3];
      accr[n] += hv.x * sWr[n * D1 + k] + hv.y * sWr[n * D1 + k + 1] +
                 hv.z * sWr[n * D1 + k + 2] + hv.w * sWr[n * D1 + k + 3];
    }
  }
#pragma unroll
  for (int n = 0; n < 5; ++n) {
    t[(size_t)i * D2 + n] = accl[n];
    r[(size_t)i * D2 + n] = accr[n];
  }
}

// ---------------------------------------------------------------- layer-2 agg + epilogue
__global__ __launch_bounds__(256) void k_layer2(
    const float* __restrict__ t, const float* __restrict__ r,
    const int* __restrict__ esort, const int* __restrict__ cur,
    const float* __restrict__ inv, const float* __restrict__ b2l,
    float* __restrict__ out) {
  const int i = blockIdx.x * blockDim.x + threadIdx.x;
  if (i >= NN) return;
  float acc[5] = {};
  int e = (i == 0) ? 0 : cur[i - 1];
  const int end = cur[i];
  for (; e < end; ++e) {
    const float* tp = t + (size_t)esort[e] * D2;
#pragma unroll
    for (int n = 0; n < 5; ++n) acc[n] += tp[n];
  }
  const float sc = inv[i];
  const float* rp = r + (size_t)i * D2;
#pragma unroll
  for (int n = 0; n < 5; ++n)
    out[(size_t)i * D2 + n] = fmaxf(acc[n] * sc + b2l[n] + rp[n], 0.f);
}

extern "C" void kernel_launch(void* const* d_in, const int* in_sizes, int n_in,
                              void* d_out, int out_size, void* d_ws,
                              size_t ws_size, hipStream_t stream) {
  const float* x   = (const float*)d_in[0];
  const int*   ei  = (const int*)d_in[1];
  const int*   src = ei;
  const int*   dst = ei + NE;
  const float* W1l = (const float*)d_in[2];
  const float* b1l = (const float*)d_in[3];
  const float* W1r = (const float*)d_in[4];
  const float* W2l = (const float*)d_in[5];
  const float* b2l = (const float*)d_in[6];
  const float* W2r = (const float*)d_in[7];
  float* out = (float*)d_out;

  // workspace layout (4-byte units)
  int*   deg   = (int*)d_ws;                 // NN
  int*   cur   = deg + NN;                   // NN
  int*   bsum  = cur + NN;                   // NB (196) + pad to 256
  int*   esort = bsum + 256;                 // NE
  float* inv   = (float*)(esort + NE);       // NN
  float* mean  = inv + NN;                   // NN*D0
  float* h     = mean + (size_t)NN * D0;     // NN*D1
  float* t     = mean;                       // alias: mean dead after k_gemm1
  float* r     = mean + (size_t)NN * D2;     // alias

  hipMemsetAsync(deg, 0, (size_t)NN * sizeof(int), stream);

  k_hist<<<(NE + 255) / 256, 256, 0, stream>>>(dst, deg);
  k_scanA<<<NB, 256, 0, stream>>>(deg, cur, bsum);
  k_scanB<<<NB, 256, 0, stream>>>(deg, bsum, cur, inv);
  k_sortedges<<<(NE + 255) / 256, 256, 0, stream>>>(src, dst, cur, esort);
  k_agg1<<<(NN * 64 + 255) / 256, 256, 0, stream>>>(x, esort, cur, inv, mean);
  dim3 g1(4, (NN + 63) / 64);
  k_gemm1<<<g1, 256, 0, stream>>>(mean, x, W1l, W1r, b1l, h);
  k_lin2<<<(NN + 255) / 256, 256, 0, stream>>>(h, W2l, W2r, t, r);
  k_layer2<<<(NN + 255) / 256, 256, 0, stream>>>(t, r, esort, cur, inv, b2l, out);
}

// Round 4
// 294.792 us; speedup vs baseline: 6.0557x; 1.2308x over previous
//
#include <hip/hip_runtime.h>

static constexpr int NN = 50000;   // nodes
static constexpr int NE = 800000;  // edges
static constexpr int D0 = 128;     // in dim
static constexpr int D1 = 256;     // hidden
static constexpr int D2 = 5;       // out
static constexpr int NB = (NN + 255) / 256;  // 196 scan blocks

using short8  = __attribute__((ext_vector_type(8))) short;
using floatx4 = __attribute__((ext_vector_type(4))) float;

__device__ __forceinline__ unsigned short f2b(float f) {
  union { float f; unsigned u; } v; v.f = f;
  unsigned r = v.u + 0x7fffu + ((v.u >> 16) & 1u);  // RNE
  return (unsigned short)(r >> 16);
}
__device__ __forceinline__ float b2f(unsigned short s) {
  union { unsigned u; float f; } v; v.u = ((unsigned)s) << 16;
  return v.f;
}

// ---------------------------------------------------------------- CSR build
__global__ __launch_bounds__(256) void k_hist(const int* __restrict__ dst,
                                              int* __restrict__ deg) {
  int e = blockIdx.x * blockDim.x + threadIdx.x;
  if (e < NE) atomicAdd(&deg[dst[e]], 1);
}

__global__ __launch_bounds__(256) void k_scanA(const int* __restrict__ deg,
                                               int* __restrict__ cur,
                                               int* __restrict__ bsum) {
  __shared__ int s[256];
  const int t = threadIdx.x;
  const int i = blockIdx.x * 256 + t;
  const int v = (i < NN) ? deg[i] : 0;
  s[t] = v;
  __syncthreads();
  for (int d = 1; d < 256; d <<= 1) {
    int u = (t >= d) ? s[t - d] : 0;
    __syncthreads();
    s[t] += u;
    __syncthreads();
  }
  if (i < NN) cur[i] = s[t] - v;
  if (t == 255) bsum[blockIdx.x] = s[255];
}

__global__ __launch_bounds__(256) void k_scanB(const int* __restrict__ deg,
                                               const int* __restrict__ bsum,
                                               int* __restrict__ cur,
                                               float* __restrict__ inv) {
  __shared__ int s[256];
  const int t = threadIdx.x;
  s[t] = (t < NB) ? bsum[t] : 0;
  __syncthreads();
  for (int d = 1; d < 256; d <<= 1) {
    int u = (t >= d) ? s[t - d] : 0;
    __syncthreads();
    s[t] += u;
    __syncthreads();
  }
  const int boff = (blockIdx.x == 0) ? 0 : s[blockIdx.x - 1];
  const int i = blockIdx.x * 256 + t;
  if (i < NN) {
    cur[i] += boff;
    inv[i] = 1.0f / (float)max(deg[i], 1);
  }
}

__global__ __launch_bounds__(256) void k_sortedges(const int* __restrict__ src,
                                                   const int* __restrict__ dst,
                                                   int* __restrict__ cur,
                                                   int* __restrict__ esort) {
  int e = blockIdx.x * blockDim.x + threadIdx.x;
  if (e < NE) {
    int p = atomicAdd(&cur[dst[e]], 1);
    esort[p] = src[e];
  }
}

// ---------------------------------------------------------------- x -> bf16
// ab[node][256] bf16: cols 128..255 = x (here); cols 0..127 = mean (k_agg1)
__global__ __launch_bounds__(256) void k_cvtx(const float* __restrict__ x,
                                              unsigned short* __restrict__ ab) {
  int idx = blockIdx.x * 256 + threadIdx.x;  // NN*32 threads
  if (idx >= NN * (D0 / 4)) return;
  int node = idx >> 5, cg = idx & 31;
  float4 v = *(const float4*)(x + (size_t)node * D0 + cg * 4);
  ushort4 o;
  o.x = f2b(v.x); o.y = f2b(v.y); o.z = f2b(v.z); o.w = f2b(v.w);
  *(ushort4*)(ab + (size_t)node * 256 + 128 + cg * 4) = o;
}

// wb[col][256] bf16: k<128 from W1l[col][k], k>=128 from W1r[col][k-128]
__global__ __launch_bounds__(256) void k_cvtw(const float* __restrict__ W1l,
                                              const float* __restrict__ W1r,
                                              unsigned short* __restrict__ wb) {
  int idx = blockIdx.x * 256 + threadIdx.x;  // 256*64 threads
  if (idx >= D1 * 64) return;
  int c = idx >> 6, k = (idx & 63) * 4;
  const float* srcp = (k < 128) ? (W1l + (size_t)c * 128 + k)
                                : (W1r + (size_t)c * 128 + (k - 128));
  float4 v = *(const float4*)srcp;
  ushort4 o;
  o.x = f2b(v.x); o.y = f2b(v.y); o.z = f2b(v.z); o.w = f2b(v.w);
  *(ushort4*)(wb + (size_t)c * 256 + k) = o;
}

// ---------------------------------------------------------------- aggregate 1
// one wave per node; lane covers 2 bf16. reads x half of ab, writes mean half.
__global__ __launch_bounds__(256) void k_agg1(
    unsigned short* __restrict__ ab, const int* __restrict__ esort,
    const int* __restrict__ cur, const float* __restrict__ inv) {
  const int i = (blockIdx.x * 256 + threadIdx.x) >> 6;
  const int lane = threadIdx.x & 63;
  if (i >= NN) return;
  int e = (i == 0) ? 0 : cur[i - 1];
  const int end = cur[i];
  float a0 = 0.f, b0 = 0.f, a1 = 0.f, b1 = 0.f;
  const unsigned short* xb = ab + 128 + lane * 2;
  for (; e + 1 < end; e += 2) {
    const unsigned v0 = *(const unsigned*)(xb + (size_t)esort[e] * 256);
    const unsigned v1 = *(const unsigned*)(xb + (size_t)esort[e + 1] * 256);
    a0 += b2f((unsigned short)v0); b0 += b2f((unsigned short)(v0 >> 16));
    a1 += b2f((unsigned short)v1); b1 += b2f((unsigned short)(v1 >> 16));
  }
  if (e < end) {
    const unsigned v0 = *(const unsigned*)(xb + (size_t)esort[e] * 256);
    a0 += b2f((unsigned short)v0); b0 += b2f((unsigned short)(v0 >> 16));
  }
  const float sc = inv[i];
  const unsigned out =
      ((unsigned)f2b((b0 + b1) * sc) << 16) | (unsigned)f2b((a0 + a1) * sc);
  *(unsigned*)(ab + (size_t)i * 256 + lane * 2) = out;
}

// ---------------------------------------------------------------- GEMM 1 (MFMA)
// hb = relu( ab[50000,256] @ wb[256,256]^T + b1l )  in bf16 out
// block: 64x64 tile, 4 waves; wave w -> cols w*16..w*16+15, 4 stacked 16x16 m-tiles
__global__ __launch_bounds__(256) void k_gemm1(
    const unsigned short* __restrict__ ab, const unsigned short* __restrict__ wb,
    const float* __restrict__ b1l, unsigned short* __restrict__ hb) {
  __shared__ short sA[64 * 40];  // [row][k], stride 40 shorts (80B: 2-way max)
  __shared__ short sB[64 * 40];  // [col][k]
  const int tid = threadIdx.x;
  const int row0 = blockIdx.y * 64;
  const int col0 = blockIdx.x * 64;
  const int wave = tid >> 6, lane = tid & 63;
  const int quad = lane >> 4, m16 = lane & 15;
  const int lr = tid >> 2;       // 0..63
  const int lk = (tid & 3) * 8;  // 0,8,16,24

  floatx4 acc[4] = {{0, 0, 0, 0}, {0, 0, 0, 0}, {0, 0, 0, 0}, {0, 0, 0, 0}};

  const int gr = row0 + lr;
  const bool aok = gr < NN;
  const unsigned short* aptr = ab + (size_t)gr * 256 + lk;
  const unsigned short* bptr = wb + (size_t)(col0 + lr) * 256 + lk;
  short* sAw = &sA[lr * 40 + lk];
  short* sBw = &sB[lr * 40 + lk];
  const uint4 zz = make_uint4(0, 0, 0, 0);

  for (int kk = 0; kk < 256; kk += 32) {
    const uint4 av = aok ? *(const uint4*)(aptr + kk) : zz;
    const uint4 bv = *(const uint4*)(bptr + kk);
    __syncthreads();  // previous iteration's ds_reads done
    *(uint4*)sAw = av;
    *(uint4*)sBw = bv;
    __syncthreads();
    const short8 bfrag = *(const short8*)&sB[(wave * 16 + m16) * 40 + quad * 8];
#pragma unroll
    for (int mt = 0; mt < 4; ++mt) {
      const short8 afrag = *(const short8*)&sA[(mt * 16 + m16) * 40 + quad * 8];
      acc[mt] =
          __builtin_amdgcn_mfma_f32_16x16x32_bf16(afrag, bfrag, acc[mt], 0, 0, 0);
    }
  }

  const int col = col0 + wave * 16 + m16;
  const float bias = b1l[col];
#pragma unroll
  for (int mt = 0; mt < 4; ++mt) {
#pragma unroll
    for (int rg = 0; rg < 4; ++rg) {
      const int row = row0 + mt * 16 + quad * 4 + rg;
      if (row < NN)
        hb[(size_t)row * 256 + col] = f2b(fmaxf(acc[mt][rg] + bias, 0.f));
    }
  }
}

// ---------------------------------------------------------------- layer-2 lin
__global__ __launch_bounds__(256) void k_lin2(
    const unsigned short* __restrict__ hb, const float* __restrict__ W2l,
    const float* __restrict__ W2r, float* __restrict__ t,
    float* __restrict__ r) {
  __shared__ float sW[2 * D2 * D1];
  for (int idx = threadIdx.x; idx < 2 * D2 * D1; idx += 256)
    sW[idx] = (idx < D2 * D1) ? W2l[idx] : W2r[idx - D2 * D1];
  __syncthreads();
  const int i = blockIdx.x * 256 + threadIdx.x;
  if (i >= NN) return;
  float accl[5] = {}, accr[5] = {};
  const unsigned short* hr = hb + (size_t)i * D1;
  for (int k = 0; k < D1; k += 8) {
    const uint4 hv = *(const uint4*)(hr + k);
    float hf[8];
    hf[0] = b2f((unsigned short)hv.x); hf[1] = b2f((unsigned short)(hv.x >> 16));
    hf[2] = b2f((unsigned short)hv.y); hf[3] = b2f((unsigned short)(hv.y >> 16));
    hf[4] = b2f((unsigned short)hv.z); hf[5] = b2f((unsigned short)(hv.z >> 16));
    hf[6] = b2f((unsigned short)hv.w); hf[7] = b2f((unsigned short)(hv.w >> 16));
#pragma unroll
    for (int n = 0; n < 5; ++n) {
      const float* wl = &sW[n * D1 + k];
      const float* wr = &sW[D2 * D1 + n * D1 + k];
#pragma unroll
      for (int j = 0; j < 8; ++j) {
        accl[n] += hf[j] * wl[j];
        accr[n] += hf[j] * wr[j];
      }
    }
  }
#pragma unroll
  for (int n = 0; n < 5; ++n) {
    t[(size_t)i * D2 + n] = accl[n];
    r[(size_t)i * D2 + n] = accr[n];
  }
}

// ---------------------------------------------------------------- layer-2 agg
__global__ __launch_bounds__(256) void k_layer2(
    const float* __restrict__ t, const float* __restrict__ r,
    const int* __restrict__ esort, const int* __restrict__ cur,
    const float* __restrict__ inv, const float* __restrict__ b2l,
    float* __restrict__ out) {
  const int i = blockIdx.x * blockDim.x + threadIdx.x;
  if (i >= NN) return;
  float acc[5] = {};
  int e = (i == 0) ? 0 : cur[i - 1];
  const int end = cur[i];
  for (; e < end; ++e) {
    const float* tp = t + (size_t)esort[e] * D2;
#pragma unroll
    for (int n = 0; n < 5; ++n) acc[n] += tp[n];
  }
  const float sc = inv[i];
  const float* rp = r + (size_t)i * D2;
#pragma unroll
  for (int n = 0; n < 5; ++n)
    out[(size_t)i * D2 + n] = fmaxf(acc[n] * sc + b2l[n] + rp[n], 0.f);
}

extern "C" void kernel_launch(void* const* d_in, const int* in_sizes, int n_in,
                              void* d_out, int out_size, void* d_ws,
                              size_t ws_size, hipStream_t stream) {
  const float* x   = (const float*)d_in[0];
  const int*   ei  = (const int*)d_in[1];
  const int*   src = ei;
  const int*   dst = ei + NE;
  const float* W1l = (const float*)d_in[2];
  const float* b1l = (const float*)d_in[3];
  const float* W1r = (const float*)d_in[4];
  const float* W2l = (const float*)d_in[5];
  const float* b2l = (const float*)d_in[6];
  const float* W2r = (const float*)d_in[7];
  float* out = (float*)d_out;

  // workspace layout (4-byte units)
  int*   deg   = (int*)d_ws;                     // NN
  int*   cur   = deg + NN;                       // NN
  int*   bsum  = cur + NN;                       // 256
  int*   esort = bsum + 256;                     // NE
  float* inv   = (float*)(esort + NE);           // NN
  unsigned short* ab = (unsigned short*)(inv + NN);        // NN*256 bf16
  unsigned short* wb = ab + (size_t)NN * 256;              // 256*256 bf16
  unsigned short* hb = wb + (size_t)D1 * 256;              // NN*256 bf16
  float* t = (float*)(hb + (size_t)NN * 256);              // NN*5
  float* r = t + (size_t)NN * D2;                          // NN*5

  hipMemsetAsync(deg, 0, (size_t)NN * sizeof(int), stream);

  k_hist<<<(NE + 255) / 256, 256, 0, stream>>>(dst, deg);
  k_scanA<<<NB, 256, 0, stream>>>(deg, cur, bsum);
  k_scanB<<<NB, 256, 0, stream>>>(deg, bsum, cur, inv);
  k_sortedges<<<(NE + 255) / 256, 256, 0, stream>>>(src, dst, cur, esort);
  k_cvtx<<<(NN * 32 + 255) / 256, 256, 0, stream>>>(x, ab);
  k_cvtw<<<(D1 * 64 + 255) / 256, 256, 0, stream>>>(W1l, W1r, wb);
  k_agg1<<<(NN * 64 + 255) / 256, 256, 0, stream>>>(ab, esort, cur, inv);
  dim3 g1(4, (NN + 63) / 64);
  k_gemm1<<<g1, 256, 0, stream>>>(ab, wb, b1l, hb);
  k_lin2<<<(NN + 255) / 256, 256, 0, stream>>>(hb, W2l, W2r, t, r);
  k_layer2<<<(NN + 255) / 256, 256, 0, stream>>>(t, r, esort, cur, inv, b2l, out);
}

// Round 5
// 276.252 us; speedup vs baseline: 6.4621x; 1.0671x over previous
//
#include <hip/hip_runtime.h>

static constexpr int NN = 50000;   // nodes
static constexpr int NE = 800000;  // edges
static constexpr int D0 = 128;     // in dim
static constexpr int D1 = 256;     // hidden
static constexpr int D2 = 5;       // out
static constexpr int NB = (NN + 255) / 256;  // 196 scan blocks

// fused prep grid partition
static constexpr int HB = (NE + 255) / 256;        // 3125 hist blocks
static constexpr int XB = (NN * 32 + 255) / 256;   // 6250 cvtx blocks
static constexpr int WB = (D1 * 64) / 256;         // 64 cvtw blocks

using short8  = __attribute__((ext_vector_type(8))) short;
using floatx4 = __attribute__((ext_vector_type(4))) float;

__device__ __forceinline__ unsigned short f2b(float f) {
  union { float f; unsigned u; } v; v.f = f;
  unsigned r = v.u + 0x7fffu + ((v.u >> 16) & 1u);  // RNE
  return (unsigned short)(r >> 16);
}
__device__ __forceinline__ float b2f(unsigned short s) {
  union { unsigned u; float f; } v; v.u = ((unsigned)s) << 16;
  return v.f;
}

// ------------------------------------------------- fused prep: hist|cvtx|cvtw
__global__ __launch_bounds__(256) void k_prep(
    const int* __restrict__ dst, int* __restrict__ deg,
    const float* __restrict__ x, unsigned short* __restrict__ ab,
    const float* __restrict__ W1l, const float* __restrict__ W1r,
    unsigned short* __restrict__ wb) {
  const int b = blockIdx.x, t = threadIdx.x;
  if (b < HB) {  // histogram of dst
    int e = b * 256 + t;
    if (e < NE) atomicAdd(&deg[dst[e]], 1);
  } else if (b < HB + XB) {  // x -> bf16 into ab cols 128..255
    int idx = (b - HB) * 256 + t;
    if (idx < NN * 32) {
      int node = idx >> 5, cg = idx & 31;
      float4 v = *(const float4*)(x + (size_t)node * D0 + cg * 4);
      ushort4 o;
      o.x = f2b(v.x); o.y = f2b(v.y); o.z = f2b(v.z); o.w = f2b(v.w);
      *(ushort4*)(ab + (size_t)node * 256 + 128 + cg * 4) = o;
    }
  } else {  // [W1l|W1r] -> bf16 wb[col][256]
    int idx = (b - HB - XB) * 256 + t;
    int c = idx >> 6, k = (idx & 63) * 4;
    const float* srcp = (k < 128) ? (W1l + (size_t)c * 128 + k)
                                  : (W1r + (size_t)c * 128 + (k - 128));
    float4 v = *(const float4*)srcp;
    ushort4 o;
    o.x = f2b(v.x); o.y = f2b(v.y); o.z = f2b(v.z); o.w = f2b(v.w);
    *(ushort4*)(wb + (size_t)c * 256 + k) = o;
  }
}

// ---------------------------------------------------------------- scan
__global__ __launch_bounds__(256) void k_scanA(const int* __restrict__ deg,
                                               int* __restrict__ cur,
                                               int* __restrict__ bsum) {
  __shared__ int s[256];
  const int t = threadIdx.x;
  const int i = blockIdx.x * 256 + t;
  const int v = (i < NN) ? deg[i] : 0;
  s[t] = v;
  __syncthreads();
  for (int d = 1; d < 256; d <<= 1) {
    int u = (t >= d) ? s[t - d] : 0;
    __syncthreads();
    s[t] += u;
    __syncthreads();
  }
  if (i < NN) cur[i] = s[t] - v;
  if (t == 255) bsum[blockIdx.x] = s[255];
}

__global__ __launch_bounds__(256) void k_scanB(const int* __restrict__ deg,
                                               const int* __restrict__ bsum,
                                               int* __restrict__ cur,
                                               float* __restrict__ inv) {
  __shared__ int s[256];
  const int t = threadIdx.x;
  s[t] = (t < NB) ? bsum[t] : 0;
  __syncthreads();
  for (int d = 1; d < 256; d <<= 1) {
    int u = (t >= d) ? s[t - d] : 0;
    __syncthreads();
    s[t] += u;
    __syncthreads();
  }
  const int boff = (blockIdx.x == 0) ? 0 : s[blockIdx.x - 1];
  const int i = blockIdx.x * 256 + t;
  if (i < NN) {
    cur[i] += boff;
    inv[i] = 1.0f / (float)max(deg[i], 1);
  }
}

__global__ __launch_bounds__(256) void k_sortedges(const int* __restrict__ src,
                                                   const int* __restrict__ dst,
                                                   int* __restrict__ cur,
                                                   int* __restrict__ esort) {
  int e = blockIdx.x * blockDim.x + threadIdx.x;
  if (e < NE) {
    int p = atomicAdd(&cur[dst[e]], 1);
    esort[p] = src[e];
  }
}

// ---------------------------------------------------------------- aggregate 1
// one wave per node; lane covers 2 bf16 cols. unroll-4 for MLP.
__global__ __launch_bounds__(256) void k_agg1(
    unsigned short* __restrict__ ab, const int* __restrict__ esort,
    const int* __restrict__ cur, const float* __restrict__ inv) {
  const int i = (blockIdx.x * 256 + threadIdx.x) >> 6;
  const int lane = threadIdx.x & 63;
  if (i >= NN) return;
  int e = (i == 0) ? 0 : cur[i - 1];
  const int end = cur[i];
  float a0 = 0.f, b0 = 0.f, a1 = 0.f, b1 = 0.f;
  float a2 = 0.f, b2 = 0.f, a3 = 0.f, b3 = 0.f;
  const unsigned short* xb = ab + 128 + lane * 2;
  for (; e + 3 < end; e += 4) {
    const int s0 = esort[e], s1 = esort[e + 1];
    const int s2 = esort[e + 2], s3 = esort[e + 3];
    const unsigned v0 = *(const unsigned*)(xb + (size_t)s0 * 256);
    const unsigned v1 = *(const unsigned*)(xb + (size_t)s1 * 256);
    const unsigned v2 = *(const unsigned*)(xb + (size_t)s2 * 256);
    const unsigned v3 = *(const unsigned*)(xb + (size_t)s3 * 256);
    a0 += b2f((unsigned short)v0); b0 += b2f((unsigned short)(v0 >> 16));
    a1 += b2f((unsigned short)v1); b1 += b2f((unsigned short)(v1 >> 16));
    a2 += b2f((unsigned short)v2); b2 += b2f((unsigned short)(v2 >> 16));
    a3 += b2f((unsigned short)v3); b3 += b2f((unsigned short)(v3 >> 16));
  }
  for (; e < end; ++e) {
    const unsigned v0 = *(const unsigned*)(xb + (size_t)esort[e] * 256);
    a0 += b2f((unsigned short)v0); b0 += b2f((unsigned short)(v0 >> 16));
  }
  const float sc = inv[i];
  const float sa = (a0 + a1) + (a2 + a3);
  const float sb = (b0 + b1) + (b2 + b3);
  const unsigned out =
      ((unsigned)f2b(sb * sc) << 16) | (unsigned)f2b(sa * sc);
  *(unsigned*)(ab + (size_t)i * 256 + lane * 2) = out;
}

// ---------------------------------------------------------------- GEMM 1 (MFMA)
__global__ __launch_bounds__(256) void k_gemm1(
    const unsigned short* __restrict__ ab, const unsigned short* __restrict__ wb,
    const float* __restrict__ b1l, unsigned short* __restrict__ hb) {
  __shared__ short sA[64 * 40];  // [row][k], stride 40 shorts
  __shared__ short sB[64 * 40];  // [col][k]
  const int tid = threadIdx.x;
  const int row0 = blockIdx.y * 64;
  const int col0 = blockIdx.x * 64;
  const int wave = tid >> 6, lane = tid & 63;
  const int quad = lane >> 4, m16 = lane & 15;
  const int lr = tid >> 2;
  const int lk = (tid & 3) * 8;

  floatx4 acc[4] = {{0, 0, 0, 0}, {0, 0, 0, 0}, {0, 0, 0, 0}, {0, 0, 0, 0}};

  const int gr = row0 + lr;
  const bool aok = gr < NN;
  const unsigned short* aptr = ab + (size_t)gr * 256 + lk;
  const unsigned short* bptr = wb + (size_t)(col0 + lr) * 256 + lk;
  short* sAw = &sA[lr * 40 + lk];
  short* sBw = &sB[lr * 40 + lk];
  const uint4 zz = make_uint4(0, 0, 0, 0);

  for (int kk = 0; kk < 256; kk += 32) {
    const uint4 av = aok ? *(const uint4*)(aptr + kk) : zz;
    const uint4 bv = *(const uint4*)(bptr + kk);
    __syncthreads();
    *(uint4*)sAw = av;
    *(uint4*)sBw = bv;
    __syncthreads();
    const short8 bfrag = *(const short8*)&sB[(wave * 16 + m16) * 40 + quad * 8];
#pragma unroll
    for (int mt = 0; mt < 4; ++mt) {
      const short8 afrag = *(const short8*)&sA[(mt * 16 + m16) * 40 + quad * 8];
      acc[mt] =
          __builtin_amdgcn_mfma_f32_16x16x32_bf16(afrag, bfrag, acc[mt], 0, 0, 0);
    }
  }

  const int col = col0 + wave * 16 + m16;
  const float bias = b1l[col];
#pragma unroll
  for (int mt = 0; mt < 4; ++mt) {
#pragma unroll
    for (int rg = 0; rg < 4; ++rg) {
      const int row = row0 + mt * 16 + quad * 4 + rg;
      if (row < NN)
        hb[(size_t)row * 256 + col] = f2b(fmaxf(acc[mt][rg] + bias, 0.f));
    }
  }
}

// ---------------------------------------------------------------- layer-2 lin
__global__ __launch_bounds__(256) void k_lin2(
    const unsigned short* __restrict__ hb, const float* __restrict__ W2l,
    const float* __restrict__ W2r, float* __restrict__ t,
    float* __restrict__ r) {
  __shared__ float sW[2 * D2 * D1];
  for (int idx = threadIdx.x; idx < 2 * D2 * D1; idx += 256)
    sW[idx] = (idx < D2 * D1) ? W2l[idx] : W2r[idx - D2 * D1];
  __syncthreads();
  const int i = blockIdx.x * 256 + threadIdx.x;
  if (i >= NN) return;
  float accl[5] = {}, accr[5] = {};
  const unsigned short* hr = hb + (size_t)i * D1;
  for (int k = 0; k < D1; k += 8) {
    const uint4 hv = *(const uint4*)(hr + k);
    float hf[8];
    hf[0] = b2f((unsigned short)hv.x); hf[1] = b2f((unsigned short)(hv.x >> 16));
    hf[2] = b2f((unsigned short)hv.y); hf[3] = b2f((unsigned short)(hv.y >> 16));
    hf[4] = b2f((unsigned short)hv.z); hf[5] = b2f((unsigned short)(hv.z >> 16));
    hf[6] = b2f((unsigned short)hv.w); hf[7] = b2f((unsigned short)(hv.w >> 16));
#pragma unroll
    for (int n = 0; n < 5; ++n) {
      const float* wl = &sW[n * D1 + k];
      const float* wr = &sW[D2 * D1 + n * D1 + k];
#pragma unroll
      for (int j = 0; j < 8; ++j) {
        accl[n] += hf[j] * wl[j];
        accr[n] += hf[j] * wr[j];
      }
    }
  }
#pragma unroll
  for (int n = 0; n < 5; ++n) {
    t[(size_t)i * D2 + n] = accl[n];
    r[(size_t)i * D2 + n] = accr[n];
  }
}

// ---------------------------------------------------------------- layer-2 agg
__global__ __launch_bounds__(256) void k_layer2(
    const float* __restrict__ t, const float* __restrict__ r,
    const int* __restrict__ esort, const int* __restrict__ cur,
    const float* __restrict__ inv, const float* __restrict__ b2l,
    float* __restrict__ out) {
  const int i = blockIdx.x * blockDim.x + threadIdx.x;
  if (i >= NN) return;
  float acc[5] = {};
  int e = (i == 0) ? 0 : cur[i - 1];
  const int end = cur[i];
  for (; e < end; ++e) {
    const float* tp = t + (size_t)esort[e] * D2;
#pragma unroll
    for (int n = 0; n < 5; ++n) acc[n] += tp[n];
  }
  const float sc = inv[i];
  const float* rp = r + (size_t)i * D2;
#pragma unroll
  for (int n = 0; n < 5; ++n)
    out[(size_t)i * D2 + n] = fmaxf(acc[n] * sc + b2l[n] + rp[n], 0.f);
}

extern "C" void kernel_launch(void* const* d_in, const int* in_sizes, int n_in,
                              void* d_out, int out_size, void* d_ws,
                              size_t ws_size, hipStream_t stream) {
  const float* x   = (const float*)d_in[0];
  const int*   ei  = (const int*)d_in[1];
  const int*   src = ei;
  const int*   dst = ei + NE;
  const float* W1l = (const float*)d_in[2];
  const float* b1l = (const float*)d_in[3];
  const float* W1r = (const float*)d_in[4];
  const float* W2l = (const float*)d_in[5];
  const float* b2l = (const float*)d_in[6];
  const float* W2r = (const float*)d_in[7];
  float* out = (float*)d_out;

  // workspace layout (4-byte units)
  int*   deg   = (int*)d_ws;                     // NN
  int*   cur   = deg + NN;                       // NN
  int*   bsum  = cur + NN;                       // 256
  int*   esort = bsum + 256;                     // NE
  float* inv   = (float*)(esort + NE);           // NN
  unsigned short* ab = (unsigned short*)(inv + NN);        // NN*256 bf16
  unsigned short* wb = ab + (size_t)NN * 256;              // 256*256 bf16
  unsigned short* hb = wb + (size_t)D1 * 256;              // NN*256 bf16
  float* t = (float*)(hb + (size_t)NN * 256);              // NN*5
  float* r = t + (size_t)NN * D2;                          // NN*5

  hipMemsetAsync(deg, 0, (size_t)NN * sizeof(int), stream);

  k_prep<<<HB + XB + WB, 256, 0, stream>>>(dst, deg, x, ab, W1l, W1r, wb);
  k_scanA<<<NB, 256, 0, stream>>>(deg, cur, bsum);
  k_scanB<<<NB, 256, 0, stream>>>(deg, bsum, cur, inv);
  k_sortedges<<<(NE + 255) / 256, 256, 0, stream>>>(src, dst, cur, esort);
  k_agg1<<<(NN * 64 + 255) / 256, 256, 0, stream>>>(ab, esort, cur, inv);
  dim3 g1(4, (NN + 63) / 64);
  k_gemm1<<<g1, 256, 0, stream>>>(ab, wb, b1l, hb);
  k_lin2<<<(NN + 255) / 256, 256, 0, stream>>>(hb, W2l, W2r, t, r);
  k_layer2<<<(NN + 255) / 256, 256, 0, stream>>>(t, r, esort, cur, inv, b2l, out);
}